// Round 1
// baseline (971.985 us; speedup 1.0000x reference)
//
#include <hip/hip_runtime.h>

#define NROWS 150000

#define SQK0f 0.05103103630798288f   // 1/sqrt(384)
#define SQK1f 0.04419417382415922f   // 1/sqrt(512)
#define IS3f  0.5773502691896258f    // 1/sqrt(3)
#define IS2f  0.7071067811865476f    // 1/sqrt(2)

typedef __attribute__((ext_vector_type(8))) short short8;
typedef __attribute__((ext_vector_type(4))) float floatx4;

// fp32 -> bf16 bits, round-to-nearest-even
__device__ __host__ inline short f2bf(float f) {
    union { float f; unsigned u; } v;
    v.f = f;
    unsigned u = v.u;
    unsigned r = (u + 0x7FFFu + ((u >> 16) & 1u)) >> 16;
    return (short)(r & 0xFFFFu);
}

// Pack weights into MFMA B-fragment order.
// W1 (K=384, N=256) = [w000 (256x256); w110 (128x256)]  -> 12 kb x 16 nt frag blocks
// W2 (K=512, N=128) = [w011 (256x128); w101 (128x128); w111 (128x128)] -> 16 kb x 8 nt
// Fragment block = 64 lanes x 8 bf16; lane l holds B[k0 + (l>>4)*8 + j][n0 + (l&15)].
__global__ void prep_weights(const float* __restrict__ w000,
                             const float* __restrict__ w110,
                             const float* __restrict__ w011,
                             const float* __restrict__ w101,
                             const float* __restrict__ w111,
                             short* __restrict__ W1p,
                             short* __restrict__ W2p)
{
    const int lane = threadIdx.x;   // 64 threads
    const int bid  = blockIdx.x;    // 0..319
    const int m = lane & 15, q = lane >> 4;
    if (bid < 192) {
        const int kb = bid >> 4, nt = bid & 15;
        const int n = nt * 16 + m;
        short8 s;
#pragma unroll
        for (int j = 0; j < 8; ++j) {
            const int k = kb * 32 + q * 8 + j;
            float v = (k < 256) ? w000[k * 256 + n] : w110[(k - 256) * 256 + n];
            s[j] = f2bf(v);
        }
        *(short8*)(W1p + bid * 512 + lane * 8) = s;
    } else {
        const int b2 = bid - 192;
        const int kb = b2 >> 3, nt = b2 & 7;
        const int n = nt * 16 + m;
        short8 s;
#pragma unroll
        for (int j = 0; j < 8; ++j) {
            const int k = kb * 32 + q * 8 + j;
            float v = (k < 256) ? w011[k * 128 + n]
                    : (k < 384) ? w101[(k - 256) * 128 + n]
                                : w111[(k - 384) * 128 + n];
            s[j] = f2bf(v);
        }
        *(short8*)(W2p + b2 * 512 + lane * 8) = s;
    }
}

// One wave = 16 rows. Fully fused: single pass over x, all accumulators live.
// GEMM1: A1(16x384) @ W1(384x256) -> out0
// GEMM2: per i: A2_i(16x512) @ W2(512x128) -> out1[:, :, i]
__global__ __launch_bounds__(256, 2) void tpr_kernel(
    const float* __restrict__ x, const float* __restrict__ y,
    const float* __restrict__ b0,
    const short* __restrict__ W1p, const short* __restrict__ W2p,
    float* __restrict__ out)
{
    const int lane = threadIdx.x & 63;
    const int wid  = blockIdx.x * 4 + (threadIdx.x >> 6);
    const int R    = wid * 16;
    if (R >= NROWS) return;
    const int m = lane & 15, q = lane >> 4;
    const int row = R + m;

    const float* __restrict__ xr = x + (size_t)row * 640;
    const float4 yv = *(const float4*)(y + (size_t)row * 4);
    const float y0 = yv.x;
    const float y1c0 = yv.y, y1c1 = yv.z, y1c2 = yv.w;

    const short8* __restrict__ W1f = (const short8*)W1p;
    const short8* __restrict__ W2f = (const short8*)W2p;

    floatx4 acc1[16];
    floatx4 acc2[3][8];
#pragma unroll
    for (int nt = 0; nt < 16; ++nt) acc1[nt] = (floatx4){0.f, 0.f, 0.f, 0.f};
#pragma unroll
    for (int i = 0; i < 3; ++i)
#pragma unroll
        for (int nt = 0; nt < 8; ++nt) acc2[i][nt] = (floatx4){0.f, 0.f, 0.f, 0.f};

    // ---------- x0 pass: K-blocks 0..7 of both GEMMs ----------
#pragma unroll
    for (int kb = 0; kb < 8; ++kb) {
        const int k0 = kb * 32 + q * 8;
        float4 a0 = *(const float4*)(xr + k0);
        float4 a1 = *(const float4*)(xr + k0 + 4);
        float xv[8] = {a0.x, a0.y, a0.z, a0.w, a1.x, a1.y, a1.z, a1.w};
        short8 af0, af1, af2, af3;
#pragma unroll
        for (int j = 0; j < 8; ++j) {
            af0[j] = f2bf(xv[j] * y0);    // -> p000
            af1[j] = f2bf(xv[j] * y1c0);  // -> p011 i=0
            af2[j] = f2bf(xv[j] * y1c1);  // -> p011 i=1
            af3[j] = f2bf(xv[j] * y1c2);  // -> p011 i=2
        }
#pragma unroll
        for (int nt = 0; nt < 16; ++nt) {
            short8 bf = W1f[(kb * 16 + nt) * 64 + lane];
            acc1[nt] = __builtin_amdgcn_mfma_f32_16x16x32_bf16(af0, bf, acc1[nt], 0, 0, 0);
        }
#pragma unroll
        for (int nt = 0; nt < 8; ++nt) {
            short8 bf = W2f[(kb * 8 + nt) * 64 + lane];
            acc2[0][nt] = __builtin_amdgcn_mfma_f32_16x16x32_bf16(af1, bf, acc2[0][nt], 0, 0, 0);
            acc2[1][nt] = __builtin_amdgcn_mfma_f32_16x16x32_bf16(af2, bf, acc2[1][nt], 0, 0, 0);
            acc2[2][nt] = __builtin_amdgcn_mfma_f32_16x16x32_bf16(af3, bf, acc2[2][nt], 0, 0, 0);
        }
    }

    // ---------- x1 pass: u-blocks 0..3 ----------
#pragma unroll
    for (int ub = 0; ub < 4; ++ub) {
        const int u0 = ub * 32 + q * 8;
        const float* xp = xr + 256 + 3 * u0;   // 24 consecutive floats, 16B aligned
        float f[24];
#pragma unroll
        for (int c = 0; c < 6; ++c) {
            float4 t = *(const float4*)(xp + 4 * c);
            f[4 * c + 0] = t.x; f[4 * c + 1] = t.y;
            f[4 * c + 2] = t.z; f[4 * c + 3] = t.w;
        }
        short8 at, ap0, ap1, ap2, ac0, ac1, ac2;
#pragma unroll
        for (int j = 0; j < 8; ++j) {
            const float t0 = f[3 * j], t1 = f[3 * j + 1], t2 = f[3 * j + 2];
            at[j]  = f2bf(IS3f * (t0 * y1c0 + t1 * y1c1 + t2 * y1c2)); // t110
            ap0[j] = f2bf(y0 * t0);                                    // p101 i=0
            ap1[j] = f2bf(y0 * t1);
            ap2[j] = f2bf(y0 * t2);
            ac0[j] = f2bf(IS2f * (t1 * y1c2 - t2 * y1c1));             // cross i=0
            ac1[j] = f2bf(IS2f * (t2 * y1c0 - t0 * y1c2));
            ac2[j] = f2bf(IS2f * (t0 * y1c1 - t1 * y1c0));
        }
        // GEMM1 t110 part (kb = 8+ub)
#pragma unroll
        for (int nt = 0; nt < 16; ++nt) {
            short8 bf = W1f[((8 + ub) * 16 + nt) * 64 + lane];
            acc1[nt] = __builtin_amdgcn_mfma_f32_16x16x32_bf16(at, bf, acc1[nt], 0, 0, 0);
        }
        // GEMM2 p101 part (kb = 8+ub)
#pragma unroll
        for (int nt = 0; nt < 8; ++nt) {
            short8 bf = W2f[((8 + ub) * 8 + nt) * 64 + lane];
            acc2[0][nt] = __builtin_amdgcn_mfma_f32_16x16x32_bf16(ap0, bf, acc2[0][nt], 0, 0, 0);
            acc2[1][nt] = __builtin_amdgcn_mfma_f32_16x16x32_bf16(ap1, bf, acc2[1][nt], 0, 0, 0);
            acc2[2][nt] = __builtin_amdgcn_mfma_f32_16x16x32_bf16(ap2, bf, acc2[2][nt], 0, 0, 0);
        }
        // GEMM2 cross part (kb = 12+ub)
#pragma unroll
        for (int nt = 0; nt < 8; ++nt) {
            short8 bf = W2f[((12 + ub) * 8 + nt) * 64 + lane];
            acc2[0][nt] = __builtin_amdgcn_mfma_f32_16x16x32_bf16(ac0, bf, acc2[0][nt], 0, 0, 0);
            acc2[1][nt] = __builtin_amdgcn_mfma_f32_16x16x32_bf16(ac1, bf, acc2[1][nt], 0, 0, 0);
            acc2[2][nt] = __builtin_amdgcn_mfma_f32_16x16x32_bf16(ac2, bf, acc2[2][nt], 0, 0, 0);
        }
    }

    // ---------- epilogue ----------
    // C/D layout: lane(m,q) reg r -> D[row_local = q*4 + r][col = m (within n-tile)]
#pragma unroll
    for (int r = 0; r < 4; ++r) {
        const int grow = R + q * 4 + r;
        float* __restrict__ orow = out + (size_t)grow * 640;
#pragma unroll
        for (int nt = 0; nt < 16; ++nt) {
            const int col = nt * 16 + m;
            orow[col] = SQK0f * acc1[nt][r] + b0[col];
        }
#pragma unroll
        for (int nt = 0; nt < 8; ++nt) {
            const int w = nt * 16 + m;
            const int base = 256 + 3 * w;       // out1 flat: 3*w + i
            orow[base + 0] = SQK1f * acc2[0][nt][r];
            orow[base + 1] = SQK1f * acc2[1][nt][r];
            orow[base + 2] = SQK1f * acc2[2][nt][r];
        }
    }
}

extern "C" void kernel_launch(void* const* d_in, const int* in_sizes, int n_in,
                              void* d_out, int out_size, void* d_ws, size_t ws_size,
                              hipStream_t stream)
{
    const float* x    = (const float*)d_in[0];
    const float* y    = (const float*)d_in[1];
    const float* w000 = (const float*)d_in[2];
    const float* w110 = (const float*)d_in[3];
    const float* w011 = (const float*)d_in[4];
    const float* w101 = (const float*)d_in[5];
    const float* w111 = (const float*)d_in[6];
    const float* b0   = (const float*)d_in[7];
    float* out = (float*)d_out;

    short* W1p = (short*)d_ws;              // 192 frag blocks * 512 shorts = 98304
    short* W2p = (short*)d_ws + 98304;      // 128 frag blocks * 512 shorts = 65536

    prep_weights<<<320, 64, 0, stream>>>(w000, w110, w011, w101, w111, W1p, W2p);

    const int waves  = (NROWS + 15) / 16;   // 9375
    const int blocks = (waves + 3) / 4;     // 2344 (last wave early-exits)
    tpr_kernel<<<blocks, 256, 0, stream>>>(x, y, b0, W1p, W2p, out);
}